// Round 5
// baseline (1542.879 us; speedup 1.0000x reference)
//
#include <hip/hip_runtime.h>
#include <cstdint>
#include <cstddef>

#define BB 16
#define NN 4096
#define CC 64
#define MM 1024
#define KK 64
#define HH 128
#define NEGV -1.0e30f

#define FTH 256    // producer threads (4 waves, 1/SIMD)
#define FPT 16     // points per thread PER BATCH (FTH*FPT == NN)
#define NPRODB 8   // producer blocks; each runs TWO batches interleaved (R19)
#define BATCHES 16
#define GTOT 256   // 1 block per CU
#define PSTRIDE 32 // progress counter stride in u32 (128B line per batch)

#define KC1 96     // layer-1 K dim padded (67 -> 96)
#define SA 104     // LDS stride of feat planes
#define SH 136     // LDS stride of h1 planes
#define HSTRIDE 41984  // per-half consumer LDS region

// producer LDS layout (within LBUF):
//   P4A 0..65536, P4B 65536..131072,
//   SXA 131072, SYA 135168, SZA 139264, SXB 143360, SYB 147456, SZB 151552,
//   candA 155648 (64B), candB 155712 (64B)  -> total 155776 <= 160K
#define LBUF_SZ 155776

typedef __attribute__((ext_vector_type(8))) short bf16x8;
typedef __attribute__((ext_vector_type(4))) float f32x4;
typedef __attribute__((ext_vector_type(2))) float f32x2;

__device__ __forceinline__ unsigned int f2bf(float f) {
  unsigned int u = __float_as_uint(f);
  return (u + 0x7fffu + ((u >> 16) & 1u)) >> 16;
}
__device__ __forceinline__ void split2(float f, unsigned int& h, unsigned int& l) {
  h = f2bf(f);
  float hf = __uint_as_float(h << 16);
  l = f2bf(f - hf);
}

template <int CTRL, int RM>
__device__ __forceinline__ void dpp_max64(unsigned int& hi, unsigned int& lo) {
  unsigned int shi = (unsigned int)__builtin_amdgcn_update_dpp(
      (int)hi, (int)hi, CTRL, RM, 0xf, false);
  unsigned int slo = (unsigned int)__builtin_amdgcn_update_dpp(
      (int)lo, (int)lo, CTRL, RM, 0xf, false);
  unsigned long long cur = ((unsigned long long)hi << 32) | lo;
  unsigned long long oth = ((unsigned long long)shi << 32) | slo;
  if (oth > cur) { hi = shi; lo = slo; }
}

// left-biased tournament over 16 values: winner == first-max of ascending scan
__device__ __forceinline__ void tourn16(const float* nv, float& bv, int& bj) {
  float tv[8]; int ti[8];
#pragma unroll
  for (int k = 0; k < 8; ++k) {
    bool c = nv[2 * k + 1] > nv[2 * k];
    tv[k] = c ? nv[2 * k + 1] : nv[2 * k];
    ti[k] = c ? (2 * k + 1) : (2 * k);
  }
  float uv[4]; int ui[4];
#pragma unroll
  for (int k = 0; k < 4; ++k) {
    bool c = tv[2 * k + 1] > tv[2 * k];
    uv[k] = c ? tv[2 * k + 1] : tv[2 * k];
    ui[k] = c ? ti[2 * k + 1] : ti[2 * k];
  }
  float wv2[2]; int wi2[2];
#pragma unroll
  for (int k = 0; k < 2; ++k) {
    bool c = uv[2 * k + 1] > uv[2 * k];
    wv2[k] = c ? uv[2 * k + 1] : uv[2 * k];
    wi2[k] = c ? ui[2 * k + 1] : ui[2 * k];
  }
  bool cf = wv2[1] > wv2[0];
  bv = cf ? wv2[1] : wv2[0];
  bj = cf ? wi2[1] : wi2[0];
}

// ---------------------------------------------------------------------------
// Weight prep + progress/claim init (block 0). pn computed inline by consumers.
// ---------------------------------------------------------------------------
__global__ __launch_bounds__(128) void wprep_kernel(
    const float* __restrict__ W1, const float* __restrict__ W2,
    unsigned short* __restrict__ W1Th, unsigned short* __restrict__ W1Tl,
    unsigned short* __restrict__ W2Th, unsigned short* __restrict__ W2Tl,
    unsigned int* __restrict__ progress, unsigned int* __restrict__ claim) {
  const int n = blockIdx.x, t = threadIdx.x;
  if (n == 0) {
    for (int j = t; j < BATCHES * PSTRIDE; j += 128) progress[j] = 0u;
    if (t == 0) *claim = 0u;
  }
  if (t < KC1) {
    float v = (t < 67) ? W1[(size_t)t * HH + n] : 0.0f;
    unsigned int h, l; split2(v, h, l);
    W1Th[n * KC1 + t] = (unsigned short)h;
    W1Tl[n * KC1 + t] = (unsigned short)l;
  }
  {
    float v = W2[(size_t)t * HH + n];
    unsigned int h, l; split2(v, h, l);
    W2Th[n * HH + t] = (unsigned short)h;
    W2Tl[n * HH + t] = (unsigned short)l;
  }
}

// ---------------------------------------------------------------------------
// FUSED producer-consumer kernel, R19: TWO-BATCH INTERLEAVED PRODUCERS.
// Evidence: clock ~full (MFMA-count cross-check vs MfmaUtil), so the ~800cy
// gap between the ~900cy issue model and 1720cy/iter measured is genuine
// handoff overhead (barrier wake + 2 dependent LDS round trips) at 1
// wave/SIMD. R16 (more waves) and R17 (polling) proved it can't be removed.
// R19 AMORTIZES it: each producer block runs TWO independent batches; one
// round = one FPS step for both, sharing ONE barrier, with batch A's latency
// segments (dpp chain, cand read, P4 read) overlapped by batch B's
// independent VALU work. Per-batch code & numerics identical to R18
// (same i = t + j*256 mapping, tournament, ~bi u64 tie-break) ->
// selections bit-identical, absmax 0.015625.
// Bookkeeping: wave0/lane0 owns batch A (SXa, flush t<16, release t==0),
// wave1/lane64 owns batch B (flush 64<=t<80, release t==64) — per-wave
// vmcnt tracks its own flush stores for the hand-rolled release.
// LDS 152KB producer / 84KB consumer -> 1 block/CU everywhere (unchanged).
// ---------------------------------------------------------------------------
__global__ __launch_bounds__(512, 2) void fused_kernel(
    const float* __restrict__ pos, const float* __restrict__ x,
    float* __restrict__ pos_s_ws, float* __restrict__ pos_s_out,
    const unsigned short* __restrict__ W1Th, const unsigned short* __restrict__ W1Tl,
    const unsigned short* __restrict__ W2Th, const unsigned short* __restrict__ W2Tl,
    const float* __restrict__ b1, const float* __restrict__ b2,
    float* __restrict__ out,
    unsigned int* __restrict__ progress, unsigned int* __restrict__ claim) {
#pragma clang fp contract(off)
  __shared__ __attribute__((aligned(16))) unsigned char LBUF[LBUF_SZ];
  const int t = threadIdx.x;
  const int lane = t & 63;

  if (blockIdx.x < NPRODB) {
    // ============ PRODUCER: FPS for batches bA and bB, interleaved ============
    if (t >= FTH) return;            // waves 4..7 exit; barrier counts live waves
    __builtin_amdgcn_s_setprio(3);
    const int wv = t >> 6;           // 0..3
    const int bA = blockIdx.x * 2, bB = bA + 1;
    float4* P4A = (float4*)LBUF;
    float4* P4B = (float4*)(LBUF + 65536);
    float* SXA = (float*)(LBUF + 131072);
    float* SYA = (float*)(LBUF + 135168);
    float* SZA = (float*)(LBUF + 139264);
    float* SXB = (float*)(LBUF + 143360);
    float* SYB = (float*)(LBUF + 147456);
    float* SZB = (float*)(LBUF + 151552);
    unsigned long long* candA = (unsigned long long*)(LBUF + 155648); // [2][4]
    unsigned long long* candB = (unsigned long long*)(LBUF + 155712); // [2][4]
    const float* pbA = pos + (size_t)bA * NN * 3;
    const float* pbB = pos + (size_t)bB * NN * 3;
    f32x2 pxA[8], pyA[8], pzA[8], ddA[8];
    f32x2 pxB[8], pyB[8], pzB[8], ddB[8];
#pragma unroll
    for (int j = 0; j < FPT; ++j) {
      int i = t + j * FTH;
      float ax = pbA[i * 3 + 0], ay = pbA[i * 3 + 1], az = pbA[i * 3 + 2];
      P4A[i] = make_float4(ax, ay, az, 0.0f);
      pxA[j >> 1][j & 1] = ax; pyA[j >> 1][j & 1] = ay; pzA[j >> 1][j & 1] = az;
      ddA[j >> 1][j & 1] = 3.4028234663852886e38f;
      float bx = pbB[i * 3 + 0], by = pbB[i * 3 + 1], bz = pbB[i * 3 + 2];
      P4B[i] = make_float4(bx, by, bz, 0.0f);
      pxB[j >> 1][j & 1] = bx; pyB[j >> 1][j & 1] = by; pzB[j >> 1][j & 1] = bz;
      ddB[j >> 1][j & 1] = 3.4028234663852886e38f;
    }
    __syncthreads();
    float4 cA = P4A[0];
    float sxA = cA.x, syA = cA.y, szA = cA.z;
    float4 cB = P4B[0];
    float sxB = cB.x, syB = cB.y, szB = cB.z;
    if (t == 0)  { SXA[0] = sxA; SYA[0] = syA; SZA[0] = szA; }
    if (t == 64) { SXB[0] = sxB; SYB[0] = syB; SZB[0] = szB; }

    for (int m = 1; m < MM; ++m) {
      // ---- phase A for both batches, interleaved (independent chains) ----
      f32x2 sAx = {sxA, sxA}, sAy = {syA, syA}, sAz = {szA, szA};
      f32x2 sBx = {sxB, sxB}, sBy = {syB, syB}, sBz = {szB, szB};
      float nvA[16], nvB[16];
#pragma unroll
      for (int k = 0; k < 8; ++k) {
        {
          f32x2 dx = pxA[k] - sAx, dy = pyA[k] - sAy, dz = pzA[k] - sAz;
          f32x2 d2 = (dx * dx + dy * dy) + dz * dz;   // no FMA (pragma)
          float n0 = fminf(ddA[k][0], d2[0]);
          float n1 = fminf(ddA[k][1], d2[1]);
          ddA[k][0] = n0; ddA[k][1] = n1;
          nvA[2 * k] = n0; nvA[2 * k + 1] = n1;
        }
        {
          f32x2 dx = pxB[k] - sBx, dy = pyB[k] - sBy, dz = pzB[k] - sBz;
          f32x2 d2 = (dx * dx + dy * dy) + dz * dz;
          float n0 = fminf(ddB[k][0], d2[0]);
          float n1 = fminf(ddB[k][1], d2[1]);
          ddB[k][0] = n0; ddB[k][1] = n1;
          nvB[2 * k] = n0; nvB[2 * k + 1] = n1;
        }
      }
      float bvA, bvB; int bjA, bjB;
      tourn16(nvA, bvA, bjA);
      tourn16(nvB, bvB, bjB);
      int biA = t + (bjA << 8);
      int biB = t + (bjB << 8);

      unsigned int khA = __float_as_uint(bvA), klA = ~(unsigned int)biA;
      unsigned int khB = __float_as_uint(bvB), klB = ~(unsigned int)biB;
      dpp_max64<0x111, 0xf>(khA, klA); dpp_max64<0x111, 0xf>(khB, klB);
      dpp_max64<0x112, 0xf>(khA, klA); dpp_max64<0x112, 0xf>(khB, klB);
      dpp_max64<0x114, 0xf>(khA, klA); dpp_max64<0x114, 0xf>(khB, klB);
      dpp_max64<0x118, 0xf>(khA, klA); dpp_max64<0x118, 0xf>(khB, klB);
      dpp_max64<0x142, 0xa>(khA, klA); dpp_max64<0x142, 0xa>(khB, klB);
      dpp_max64<0x143, 0xc>(khA, klA); dpp_max64<0x143, 0xc>(khB, klB);
      const int p4 = (m & 1) * 4;
      if (lane == 63) {
        candA[p4 + wv] = ((unsigned long long)khA << 32) | klA;
        candB[p4 + wv] = ((unsigned long long)khB << 32) | klB;
      }
      __syncthreads();   // ONE barrier serves both batches' exchange
      unsigned long long bestA = candA[p4 + 0];
      unsigned long long bestB = candB[p4 + 0];
#pragma unroll
      for (int w = 1; w < 4; ++w) {
        unsigned long long oA = candA[p4 + w];
        unsigned long long oB = candB[p4 + w];
        bestA = oA > bestA ? oA : bestA;
        bestB = oB > bestB ? oB : bestB;
      }
      int fiA = (int)(~(unsigned int)(bestA & 0xffffffffull));
      int fiB = (int)(~(unsigned int)(bestB & 0xffffffffull));
      float4 wA = P4A[fiA];        // two independent broadcast reads,
      float4 wB = P4B[fiB];        // issued together -> one latency
      sxA = wA.x; syA = wA.y; szA = wA.z;
      sxB = wB.x; syB = wB.y; szB = wB.z;
      if (t == 0)  { SXA[m] = sxA; SYA[m] = syA; SZA[m] = szA; }
      if (t == 64) { SXB[m] = sxB; SYB[m] = syB; SZB[m] = szB; }
      if ((m & 15) == 15) {
        // parallel flush: wave0 lanes 0..15 publish batch A, wave1 lanes
        // 64..79 publish batch B (each reads S* written by its own wave's
        // lane0 — in-wave DS ordering guarantees visibility).
        if (t < 16) {
          int idx = (m - 15) + t;
          float fx = SXA[idx], fy = SYA[idx], fz = SZA[idx];
          size_t o = ((size_t)bA * MM + idx) * 3;
          __hip_atomic_store(&pos_s_ws[o + 0], fx, __ATOMIC_RELAXED, __HIP_MEMORY_SCOPE_AGENT);
          __hip_atomic_store(&pos_s_ws[o + 1], fy, __ATOMIC_RELAXED, __HIP_MEMORY_SCOPE_AGENT);
          __hip_atomic_store(&pos_s_ws[o + 2], fz, __ATOMIC_RELAXED, __HIP_MEMORY_SCOPE_AGENT);
        } else if (t >= 64 && t < 80) {
          int idx = (m - 15) + (t - 64);
          float fx = SXB[idx], fy = SYB[idx], fz = SZB[idx];
          size_t o = ((size_t)bB * MM + idx) * 3;
          __hip_atomic_store(&pos_s_ws[o + 0], fx, __ATOMIC_RELAXED, __HIP_MEMORY_SCOPE_AGENT);
          __hip_atomic_store(&pos_s_ws[o + 1], fy, __ATOMIC_RELAXED, __HIP_MEMORY_SCOPE_AGENT);
          __hip_atomic_store(&pos_s_ws[o + 2], fz, __ATOMIC_RELAXED, __HIP_MEMORY_SCOPE_AGENT);
        }
      } else if ((m & 15) == 0) {
        // hand-rolled release: each owning wave drains ITS vmcnt (covers its
        // flush stores from one iteration ago — already retired) then
        // publishes progress with a relaxed agent store.
        if (t == 0) {
          asm volatile("s_waitcnt vmcnt(0)" ::: "memory");
          __hip_atomic_store(&progress[bA * PSTRIDE], (unsigned int)m,
                             __ATOMIC_RELAXED, __HIP_MEMORY_SCOPE_AGENT);
        }
        if (t == 64) {
          asm volatile("s_waitcnt vmcnt(0)" ::: "memory");
          __hip_atomic_store(&progress[bB * PSTRIDE], (unsigned int)m,
                             __ATOMIC_RELAXED, __HIP_MEMORY_SCOPE_AGENT);
        }
      }
    }
    __syncthreads();   // S* final values visible to all threads
    if (t == 0) {
      asm volatile("s_waitcnt vmcnt(0)" ::: "memory");
      __hip_atomic_store(&progress[bA * PSTRIDE], (unsigned int)MM,
                         __ATOMIC_RELAXED, __HIP_MEMORY_SCOPE_AGENT);
    }
    if (t == 64) {
      asm volatile("s_waitcnt vmcnt(0)" ::: "memory");
      __hip_atomic_store(&progress[bB * PSTRIDE], (unsigned int)MM,
                         __ATOMIC_RELAXED, __HIP_MEMORY_SCOPE_AGENT);
    }
    for (int i = t; i < MM; i += FTH) {
      size_t oA = ((size_t)bA * MM + i) * 3;
      pos_s_out[oA + 0] = SXA[i];
      pos_s_out[oA + 1] = SYA[i];
      pos_s_out[oA + 2] = SZA[i];
      size_t oB = ((size_t)bB * MM + i) * 3;
      pos_s_out[oB + 0] = SXB[i];
      pos_s_out[oB + 1] = SYB[i];
      pos_s_out[oB + 2] = SZB[i];
    }
    return;
  }

  // ============ CONSUMER: two 4-wave pipelines (halves h=0,1) ============
  const int h = t >> 8;            // half id
  const int th = t & 255;          // half-local thread id
  const int wvh = (t >> 6) & 3;    // half-local wave id
  unsigned char* HB = LBUF + h * HSTRIDE;
  unsigned short* Ah = (unsigned short*)HB;
  unsigned short* Al = (unsigned short*)(HB + 64 * SA * 2);
  unsigned short* Hh = (unsigned short*)HB;
  unsigned short* Hl = (unsigned short*)(HB + 64 * SH * 2);
  int* nbr_s = (int*)(HB + 34816);
  unsigned long long* masksL = (unsigned long long*)(HB + 35072);
  int* prefixL = (int*)(HB + 35584);
  float* ctr = (float*)(HB + 35840);
  int* cntS = (int*)(HB + 35856);
  volatile int* cidShare = (int*)(LBUF + 83960);   // block-wide
  const int r = lane & 15, q = lane >> 4;
  const int wbase = wvh * 32;

  while (true) {
    if (t == 0) {
      unsigned int i = __hip_atomic_fetch_add(claim, 2u, __ATOMIC_RELAXED,
                                              __HIP_MEMORY_SCOPE_AGENT);
      *cidShare = (int)i;
    }
    __syncthreads();
    int i0 = *cidShare;
    if (i0 >= BB * MM) break;                      // uniform exit
    const int i = i0 + h;
    const bool active = (i < BB * MM);
    const int cid = active ? (((i & 15) << 10) | (i >> 4)) : 0;
    const int b = cid >> 10;
    const int m = cid & 1023;

    if (active && th < 64) {   // half's wave 0 polls production progress
      while ((int)__hip_atomic_load(&progress[b * PSTRIDE], __ATOMIC_RELAXED,
                                    __HIP_MEMORY_SCOPE_AGENT) <= m)
        __builtin_amdgcn_s_sleep(64);
    }
    if (active && th < 3)
      ctr[th] = __hip_atomic_load(&pos_s_ws[(size_t)cid * 3 + th],
                                  __ATOMIC_RELAXED, __HIP_MEMORY_SCOPE_AGENT);
    __syncthreads();

    // ---- ballq: 4-wave mask pass + prefix + compaction (per half) ----
    const float sx = ctr[0], sy = ctr[1], sz = ctr[2];
    const float sn = (sx * sx + sy * sy) + sz * sz;
    const float* pb = pos + (size_t)b * NN * 3;
    if (active) {
#pragma unroll
      for (int cc = 0; cc < 16; ++cc) {
        int c = (wvh << 4) + cc;
        int n = (c << 6) + lane;
        float xx = pb[n * 3 + 0], yy = pb[n * 3 + 1], zz = pb[n * 3 + 2];
        float pnn = (xx * xx + yy * yy) + zz * zz;  // == old pn[n] bitwise
        float dot = __builtin_fmaf(sz, zz, __builtin_fmaf(sy, yy, sx * xx));
        float d2 = (sn + pnn) - 2.0f * dot;
        bool pred = d2 <= 0.04f;
        unsigned long long mask = __ballot(pred);
        if (lane == 0) masksL[c] = mask;
      }
    }
    __syncthreads();
    if (active && th < 64) {
      int pc = (int)__popcll(masksL[lane]);
      int incl = pc;
#pragma unroll
      for (int off = 1; off < 64; off <<= 1) {
        int o2 = __shfl_up(incl, off, 64);
        if (lane >= off) incl += o2;
      }
      prefixL[lane] = incl - pc;
      if (lane == 63) *cntS = incl < KK ? incl : KK;
    }
    __syncthreads();
    const int cnt = *cntS;
    if (active) {
#pragma unroll
      for (int cc = 0; cc < 16; ++cc) {
        int c = (wvh << 4) + cc;
        unsigned long long mk = masksL[c];
        bool pred = (mk >> lane) & 1ull;
        int slot = prefixL[c] + (int)__popcll(mk & ((1ull << lane) - 1ull));
        if (pred && slot < KK) nbr_s[slot] = (c << 6) + lane;
      }
    }
    __syncthreads();

    // ---- gather + hi/lo split into LDS feat planes ----
    if (active) {
      const int kn = th >> 2, p = th & 3;
      float vals[16];
      float d0 = 0.0f, d1 = 0.0f, d2v = 0.0f;
      if (kn < cnt) {
        int n = nbr_s[kn];
        const float* xp = x + ((size_t)b * NN + n) * CC + p * 16;
#pragma unroll
        for (int ii = 0; ii < 4; ++ii) {
          float4 v = ((const float4*)xp)[ii];
          vals[ii * 4 + 0] = v.x; vals[ii * 4 + 1] = v.y;
          vals[ii * 4 + 2] = v.z; vals[ii * 4 + 3] = v.w;
        }
        if (p == 0) {
          const float* pp = pos + ((size_t)b * NN + n) * 3;
          d0 = pp[0] - sx; d1 = pp[1] - sy; d2v = pp[2] - sz;
        }
      } else {
#pragma unroll
        for (int ii = 0; ii < 16; ++ii) vals[ii] = 0.0f;
      }
#pragma unroll
      for (int j = 0; j < 16; j += 2) {
        unsigned int h0, l0, h1, l1;
        split2(vals[j], h0, l0);
        split2(vals[j + 1], h1, l1);
        int c = p * 16 + j;
        *(unsigned int*)&Ah[kn * SA + c] = h0 | (h1 << 16);
        *(unsigned int*)&Al[kn * SA + c] = l0 | (l1 << 16);
      }
      if (p == 0) {
        unsigned int h0, l0, h1, l1, h2, l2;
        split2(d0, h0, l0); split2(d1, h1, l1); split2(d2v, h2, l2);
        *(unsigned int*)&Ah[kn * SA + 64] = h0 | (h1 << 16);
        *(unsigned int*)&Al[kn * SA + 64] = l0 | (l1 << 16);
        *(unsigned int*)&Ah[kn * SA + 66] = h2;
        *(unsigned int*)&Al[kn * SA + 66] = l2;
      } else if (p == 1) {
#pragma unroll
        for (int c = 68; c < 80; c += 2) {
          *(unsigned int*)&Ah[kn * SA + c] = 0u;
          *(unsigned int*)&Al[kn * SA + c] = 0u;
        }
      } else if (p == 2) {
#pragma unroll
        for (int c = 80; c < 96; c += 2) {
          *(unsigned int*)&Ah[kn * SA + c] = 0u;
          *(unsigned int*)&Al[kn * SA + c] = 0u;
        }
      }
    }
    __syncthreads();

    f32x4 acc[4][2];
#pragma unroll
    for (int mt = 0; mt < 4; ++mt)
#pragma unroll
      for (int nt = 0; nt < 2; ++nt) acc[mt][nt] = (f32x4)0.0f;

    // ---- layer 1 ----
    if (active) {
#pragma unroll
      for (int kc = 0; kc < 3; ++kc) {
        bf16x8 bh[2], bl[2];
#pragma unroll
        for (int nt = 0; nt < 2; ++nt) {
          int o = (wbase + nt * 16 + r) * KC1 + kc * 32 + q * 8;
          bh[nt] = *(const bf16x8*)(W1Th + o);
          bl[nt] = *(const bf16x8*)(W1Tl + o);
        }
#pragma unroll
        for (int mt = 0; mt < 4; ++mt) {
          int o = (mt * 16 + r) * SA + kc * 32 + q * 8;
          bf16x8 ah = *(const bf16x8*)&Ah[o];
          bf16x8 al = *(const bf16x8*)&Al[o];
#pragma unroll
          for (int nt = 0; nt < 2; ++nt) {
            acc[mt][nt] = __builtin_amdgcn_mfma_f32_16x16x32_bf16(ah, bh[nt], acc[mt][nt], 0, 0, 0);
            acc[mt][nt] = __builtin_amdgcn_mfma_f32_16x16x32_bf16(al, bh[nt], acc[mt][nt], 0, 0, 0);
            acc[mt][nt] = __builtin_amdgcn_mfma_f32_16x16x32_bf16(ah, bl[nt], acc[mt][nt], 0, 0, 0);
          }
        }
      }
    }
    __syncthreads();   // alias guard: A-plane reads done before H overwrite

    if (active) {
      float b1v[2] = { b1[wbase + r], b1[wbase + 16 + r] };
#pragma unroll
      for (int mt = 0; mt < 4; ++mt)
#pragma unroll
        for (int nt = 0; nt < 2; ++nt)
#pragma unroll
          for (int ii = 0; ii < 4; ++ii) {
            int mm = mt * 16 + q * 4 + ii;
            int n = wbase + nt * 16 + r;
            float v = fmaxf(acc[mt][nt][ii] + b1v[nt], 0.0f);
            unsigned int hh2, ll2; split2(v, hh2, ll2);
            Hh[mm * SH + n] = (unsigned short)hh2;
            Hl[mm * SH + n] = (unsigned short)ll2;
          }
    }
    __syncthreads();

    // ---- layer 2 + masked max ----
#pragma unroll
    for (int mt = 0; mt < 4; ++mt)
#pragma unroll
      for (int nt = 0; nt < 2; ++nt) acc[mt][nt] = (f32x4)0.0f;
    if (active) {
#pragma unroll
      for (int kc = 0; kc < 4; ++kc) {
        bf16x8 bh[2], bl[2];
#pragma unroll
        for (int nt = 0; nt < 2; ++nt) {
          int o = (wbase + nt * 16 + r) * HH + kc * 32 + q * 8;
          bh[nt] = *(const bf16x8*)(W2Th + o);
          bl[nt] = *(const bf16x8*)(W2Tl + o);
        }
#pragma unroll
        for (int mt = 0; mt < 4; ++mt) {
          int o = (mt * 16 + r) * SH + kc * 32 + q * 8;
          bf16x8 ah = *(const bf16x8*)&Hh[o];
          bf16x8 al = *(const bf16x8*)&Hl[o];
#pragma unroll
          for (int nt = 0; nt < 2; ++nt) {
            acc[mt][nt] = __builtin_amdgcn_mfma_f32_16x16x32_bf16(ah, bh[nt], acc[mt][nt], 0, 0, 0);
            acc[mt][nt] = __builtin_amdgcn_mfma_f32_16x16x32_bf16(al, bh[nt], acc[mt][nt], 0, 0, 0);
            acc[mt][nt] = __builtin_amdgcn_mfma_f32_16x16x32_bf16(ah, bl[nt], acc[mt][nt], 0, 0, 0);
          }
        }
      }
      float b2v[2] = { b2[wbase + r], b2[wbase + 16 + r] };
#pragma unroll
      for (int nt = 0; nt < 2; ++nt) {
        float vmax = NEGV;
#pragma unroll
        for (int mt = 0; mt < 4; ++mt)
#pragma unroll
          for (int ii = 0; ii < 4; ++ii) {
            int mm = mt * 16 + q * 4 + ii;
            float v = fmaxf(acc[mt][nt][ii] + b2v[nt], 0.0f);
            if (mm < cnt) vmax = fmaxf(vmax, v);
          }
        vmax = fmaxf(vmax, __shfl_xor(vmax, 16, 64));
        vmax = fmaxf(vmax, __shfl_xor(vmax, 32, 64));
        if (q == 0)
          out[(size_t)cid * HH + wbase + nt * 16 + r] = (cnt > 0) ? vmax : 0.0f;
      }
    }
    __syncthreads();   // LDS reuse guard before next center
  }
}

// ---------------------------------------------------------------------------
extern "C" void kernel_launch(void* const* d_in, const int* in_sizes, int n_in,
                              void* d_out, int out_size, void* d_ws, size_t ws_size,
                              hipStream_t stream) {
  const float* x   = (const float*)d_in[0];
  const float* pos = (const float*)d_in[1];
  const float* W1  = (const float*)d_in[2];
  const float* b1  = (const float*)d_in[3];
  const float* W2  = (const float*)d_in[4];
  const float* b2  = (const float*)d_in[5];
  float* out = (float*)d_out;
  float* pos_s_out = out + (size_t)BB * MM * HH;

  char* ws = (char*)d_ws;
  float* pos_s_ws = (float*)(ws);                          // 196608 B
  unsigned short* W1Th = (unsigned short*)(ws + 458752);   // 24576 B
  unsigned short* W1Tl = (unsigned short*)(ws + 483328);   // 24576 B
  unsigned short* W2Th = (unsigned short*)(ws + 507904);   // 32768 B
  unsigned short* W2Tl = (unsigned short*)(ws + 540672);   // 32768 B
  unsigned int* progress = (unsigned int*)(ws + 573440);   // 16*128 B
  unsigned int* claim    = (unsigned int*)(ws + 575488);   // 4 B

  wprep_kernel<<<HH, 128, 0, stream>>>(W1, W2, W1Th, W1Tl, W2Th, W2Tl,
                                       progress, claim);
  fused_kernel<<<GTOT, 512, 0, stream>>>(pos, x, pos_s_ws, pos_s_out,
                                         W1Th, W1Tl, W2Th, W2Tl, b1, b2, out,
                                         progress, claim);
}

// Round 6
// 1010.909 us; speedup vs baseline: 1.5262x; 1.5262x over previous
//
#include <hip/hip_runtime.h>
#include <cstdint>
#include <cstddef>

#define BB 16
#define NN 4096
#define CC 64
#define MM 1024
#define KK 64
#define HH 128
#define NEGV -1.0e30f

#define FTH 128    // R20: TWO producer waves (R16: 8 waves bad; gradient says fewer)
#define FPT 32     // points per thread (FTH*FPT == NN)
#define NPROD 16   // producer blocks (one per batch) — R19 two-batch refuted
#define GTOT 256   // 1 block per CU
#define PSTRIDE 32 // progress counter stride in u32 (128B line per batch)

#define KC1 96     // layer-1 K dim padded (67 -> 96)
#define SA 104     // LDS stride of feat planes
#define SH 136     // LDS stride of h1 planes
#define HSTRIDE 41984  // per-half consumer LDS region

typedef __attribute__((ext_vector_type(8))) short bf16x8;
typedef __attribute__((ext_vector_type(4))) float f32x4;
typedef __attribute__((ext_vector_type(2))) float f32x2;

__device__ __forceinline__ unsigned int f2bf(float f) {
  unsigned int u = __float_as_uint(f);
  return (u + 0x7fffu + ((u >> 16) & 1u)) >> 16;
}
__device__ __forceinline__ void split2(float f, unsigned int& h, unsigned int& l) {
  h = f2bf(f);
  float hf = __uint_as_float(h << 16);
  l = f2bf(f - hf);
}

template <int CTRL, int RM>
__device__ __forceinline__ void dpp_max64(unsigned int& hi, unsigned int& lo) {
  unsigned int shi = (unsigned int)__builtin_amdgcn_update_dpp(
      (int)hi, (int)hi, CTRL, RM, 0xf, false);
  unsigned int slo = (unsigned int)__builtin_amdgcn_update_dpp(
      (int)lo, (int)lo, CTRL, RM, 0xf, false);
  unsigned long long cur = ((unsigned long long)hi << 32) | lo;
  unsigned long long oth = ((unsigned long long)shi << 32) | slo;
  if (oth > cur) { hi = shi; lo = slo; }
}

// ---------------------------------------------------------------------------
// Weight prep + progress/claim init (block 0). pn computed inline by consumers.
// ---------------------------------------------------------------------------
__global__ __launch_bounds__(128) void wprep_kernel(
    const float* __restrict__ W1, const float* __restrict__ W2,
    unsigned short* __restrict__ W1Th, unsigned short* __restrict__ W1Tl,
    unsigned short* __restrict__ W2Th, unsigned short* __restrict__ W2Tl,
    unsigned int* __restrict__ progress, unsigned int* __restrict__ claim) {
  const int n = blockIdx.x, t = threadIdx.x;
  if (n == 0) {
    for (int j = t; j < NPROD * PSTRIDE; j += 128) progress[j] = 0u;
    if (t == 0) *claim = 0u;
  }
  if (t < KC1) {
    float v = (t < 67) ? W1[(size_t)t * HH + n] : 0.0f;
    unsigned int h, l; split2(v, h, l);
    W1Th[n * KC1 + t] = (unsigned short)h;
    W1Tl[n * KC1 + t] = (unsigned short)l;
  }
  {
    float v = W2[(size_t)t * HH + n];
    unsigned int h, l; split2(v, h, l);
    W2Th[n * HH + t] = (unsigned short)h;
    W2Tl[n * HH + t] = (unsigned short)l;
  }
}

// ---------------------------------------------------------------------------
// FUSED producer-consumer kernel, R20: TWO-WAVE PRODUCER.
// R19 post-mortem (734->1509): (a) __launch_bounds__(512,2) capped VGPRs at
// 128 -> two-batch state (~190 regs) spilled to scratch in the hot loop;
// (b) wall time = 1023 x round_cy regardless of batches/block, so two-batch
// was break-even at best even spill-free. Abandoned.
// Ledger: wave-count gradient is monotone (8 waves << 4 waves): per-iter cost
// is exchange+skew, scaling with participant count. R20 goes DOWN to 2 waves
// (FTH=128, FPT=32): exchange = 2 slots (ONE 16B read, ONE u64 compare),
// barrier syncs 2 waves, skew halves. Phase-A issue doubles (cheap).
// Needs ~190 VGPRs -> __launch_bounds__(512) (256 budget; the R19 lesson).
// Tournament level 1 fused into the distance loop (kills nv[32] live range).
// Numerics: i = t + j*128, bi = t + (bj<<7) == global idx, left-biased
// strict-> tournament in ascending-j order, ~bi u64 tie-break ->
// selections bit-identical, absmax 0.015625.
// ---------------------------------------------------------------------------
__global__ __launch_bounds__(512) void fused_kernel(
    const float* __restrict__ pos, const float* __restrict__ x,
    float* __restrict__ pos_s_ws, float* __restrict__ pos_s_out,
    const unsigned short* __restrict__ W1Th, const unsigned short* __restrict__ W1Tl,
    const unsigned short* __restrict__ W2Th, const unsigned short* __restrict__ W2Tl,
    const float* __restrict__ b1, const float* __restrict__ b2,
    float* __restrict__ out,
    unsigned int* __restrict__ progress, unsigned int* __restrict__ claim) {
#pragma clang fp contract(off)
  __shared__ __attribute__((aligned(16))) unsigned char LBUF[83968];
  const int t = threadIdx.x;
  const int lane = t & 63;

  if (blockIdx.x < NPROD) {
    // =================== PRODUCER: FPS for batch b (2 waves) ===================
    if (t >= FTH) return;            // waves 2..7 exit; barrier counts live waves
    __builtin_amdgcn_s_setprio(3);
    const int wv = t >> 6;           // 0..1
    const int b = blockIdx.x;
    float4* P4 = (float4*)LBUF;                          // 65536 B
    float* SXa = (float*)(LBUF + 65536);                 // 4096 B
    float* SYa = (float*)(LBUF + 69632);                 // 4096 B
    float* SZa = (float*)(LBUF + 73728);                 // 4096 B
    unsigned long long* cand = (unsigned long long*)(LBUF + 77824); // [2][2]
    const float* pb = pos + (size_t)b * NN * 3;
    f32x2 px[16], py[16], pz[16], dd[16];
#pragma unroll
    for (int j = 0; j < FPT; ++j) {
      int i = t + j * FTH;
      float xx = pb[i * 3 + 0], yy = pb[i * 3 + 1], zz = pb[i * 3 + 2];
      P4[i] = make_float4(xx, yy, zz, 0.0f);
      px[j >> 1][j & 1] = xx;
      py[j >> 1][j & 1] = yy;
      pz[j >> 1][j & 1] = zz;
      dd[j >> 1][j & 1] = 3.4028234663852886e38f;
    }
    __syncthreads();
    float4 c4 = P4[0];
    float sx = c4.x, sy = c4.y, sz = c4.z;
    if (t == 0) { SXa[0] = sx; SYa[0] = sy; SZa[0] = sz; }

    for (int m = 1; m < MM; ++m) {
      f32x2 s2x = {sx, sx}, s2y = {sy, sy}, s2z = {sz, sz};
      // distance update + tournament level 1 fused (saves nv[] live range)
      float tv[16]; int ti[16];
#pragma unroll
      for (int k = 0; k < 16; ++k) {
        f32x2 dx = px[k] - s2x, dy = py[k] - s2y, dz = pz[k] - s2z;
        f32x2 d2 = (dx * dx + dy * dy) + dz * dz;   // v_pk_*, no FMA (pragma)
        float n0 = fminf(dd[k][0], d2[0]);
        float n1 = fminf(dd[k][1], d2[1]);
        dd[k][0] = n0;
        dd[k][1] = n1;
        bool c = n1 > n0;                // left-biased: keeps first-max
        tv[k] = c ? n1 : n0;
        ti[k] = c ? (2 * k + 1) : (2 * k);
      }
      // levels 2..5
      float uv[8]; int ui[8];
#pragma unroll
      for (int k = 0; k < 8; ++k) {
        bool c = tv[2 * k + 1] > tv[2 * k];
        uv[k] = c ? tv[2 * k + 1] : tv[2 * k];
        ui[k] = c ? ti[2 * k + 1] : ti[2 * k];
      }
      float vv[4]; int vi[4];
#pragma unroll
      for (int k = 0; k < 4; ++k) {
        bool c = uv[2 * k + 1] > uv[2 * k];
        vv[k] = c ? uv[2 * k + 1] : uv[2 * k];
        vi[k] = c ? ui[2 * k + 1] : ui[2 * k];
      }
      float wv2[2]; int wi2[2];
#pragma unroll
      for (int k = 0; k < 2; ++k) {
        bool c = vv[2 * k + 1] > vv[2 * k];
        wv2[k] = c ? vv[2 * k + 1] : vv[2 * k];
        wi2[k] = c ? vi[2 * k + 1] : vi[2 * k];
      }
      bool cf = wv2[1] > wv2[0];
      float bv = cf ? wv2[1] : wv2[0];
      int bj = cf ? wi2[1] : wi2[0];
      int bi = t + (bj << 7);          // == global point index

      unsigned int kh = __float_as_uint(bv);
      unsigned int kl = ~(unsigned int)bi;
      dpp_max64<0x111, 0xf>(kh, kl);
      dpp_max64<0x112, 0xf>(kh, kl);
      dpp_max64<0x114, 0xf>(kh, kl);
      dpp_max64<0x118, 0xf>(kh, kl);
      dpp_max64<0x142, 0xa>(kh, kl);
      dpp_max64<0x143, 0xc>(kh, kl);
      const int p2 = (m & 1) * 2;
      if (lane == 63)
        cand[p2 + wv] = ((unsigned long long)kh << 32) | kl;
      __syncthreads();
      unsigned long long c0 = cand[p2 + 0];
      unsigned long long c1 = cand[p2 + 1];
      unsigned long long best = c1 > c0 ? c1 : c0;
      int fi = (int)(~(unsigned int)(best & 0xffffffffull));
      float4 w4 = P4[fi];
      sx = w4.x; sy = w4.y; sz = w4.z;
      if (t == 0) { SXa[m] = sx; SYa[m] = sy; SZa[m] = sz; }
      if ((m & 15) == 15) {
        // parallel flush: lanes 0..15 of wave0 each publish one center.
        // SXa[idx] written by lane0 of the SAME wave (in-order DS).
        if (t < 16) {
          int idx = (m - 15) + t;
          float fx = SXa[idx], fy = SYa[idx], fz = SZa[idx];
          size_t o = ((size_t)b * MM + idx) * 3;
          __hip_atomic_store(&pos_s_ws[o + 0], fx, __ATOMIC_RELAXED, __HIP_MEMORY_SCOPE_AGENT);
          __hip_atomic_store(&pos_s_ws[o + 1], fy, __ATOMIC_RELAXED, __HIP_MEMORY_SCOPE_AGENT);
          __hip_atomic_store(&pos_s_ws[o + 2], fz, __ATOMIC_RELAXED, __HIP_MEMORY_SCOPE_AGENT);
        }
      } else if ((m & 15) == 0 && t == 0) {
        // hand-rolled release: wave0's flush stores (all lanes, one wave's
        // vmcnt) complete at the coherence point before progress publishes.
        asm volatile("s_waitcnt vmcnt(0)" ::: "memory");
        __hip_atomic_store(&progress[b * PSTRIDE], (unsigned int)m,
                           __ATOMIC_RELAXED, __HIP_MEMORY_SCOPE_AGENT);
      }
    }
    __syncthreads();   // SXa/SYa/SZa final values visible to all threads
    if (t == 0) {
      // final publish: last flush (m=1023) covered centers 1008..1023.
      asm volatile("s_waitcnt vmcnt(0)" ::: "memory");
      __hip_atomic_store(&progress[b * PSTRIDE], (unsigned int)MM,
                         __ATOMIC_RELAXED, __HIP_MEMORY_SCOPE_AGENT);
    }
    for (int i = t; i < MM; i += FTH) {
      size_t o = ((size_t)b * MM + i) * 3;
      pos_s_out[o + 0] = SXa[i];
      pos_s_out[o + 1] = SYa[i];
      pos_s_out[o + 2] = SZa[i];
    }
    return;
  }

  // ============ CONSUMER: two 4-wave pipelines (halves h=0,1) ============
  const int h = t >> 8;            // half id
  const int th = t & 255;          // half-local thread id
  const int wvh = (t >> 6) & 3;    // half-local wave id
  unsigned char* HB = LBUF + h * HSTRIDE;
  unsigned short* Ah = (unsigned short*)HB;
  unsigned short* Al = (unsigned short*)(HB + 64 * SA * 2);
  unsigned short* Hh = (unsigned short*)HB;
  unsigned short* Hl = (unsigned short*)(HB + 64 * SH * 2);
  int* nbr_s = (int*)(HB + 34816);
  unsigned long long* masksL = (unsigned long long*)(HB + 35072);
  int* prefixL = (int*)(HB + 35584);
  float* ctr = (float*)(HB + 35840);
  int* cntS = (int*)(HB + 35856);
  volatile int* cidShare = (int*)(LBUF + 83960);   // block-wide
  const int r = lane & 15, q = lane >> 4;
  const int wbase = wvh * 32;

  while (true) {
    if (t == 0) {
      unsigned int i = __hip_atomic_fetch_add(claim, 2u, __ATOMIC_RELAXED,
                                              __HIP_MEMORY_SCOPE_AGENT);
      *cidShare = (int)i;
    }
    __syncthreads();
    int i0 = *cidShare;
    if (i0 >= BB * MM) break;                      // uniform exit
    const int i = i0 + h;
    const bool active = (i < BB * MM);
    const int cid = active ? (((i & 15) << 10) | (i >> 4)) : 0;
    const int b = cid >> 10;
    const int m = cid & 1023;

    if (active && th < 64) {   // half's wave 0 polls production progress
      while ((int)__hip_atomic_load(&progress[b * PSTRIDE], __ATOMIC_RELAXED,
                                    __HIP_MEMORY_SCOPE_AGENT) <= m)
        __builtin_amdgcn_s_sleep(64);
    }
    if (active && th < 3)
      ctr[th] = __hip_atomic_load(&pos_s_ws[(size_t)cid * 3 + th],
                                  __ATOMIC_RELAXED, __HIP_MEMORY_SCOPE_AGENT);
    __syncthreads();

    // ---- ballq: 4-wave mask pass + prefix + compaction (per half) ----
    const float sx = ctr[0], sy = ctr[1], sz = ctr[2];
    const float sn = (sx * sx + sy * sy) + sz * sz;
    const float* pb = pos + (size_t)b * NN * 3;
    if (active) {
#pragma unroll
      for (int cc = 0; cc < 16; ++cc) {
        int c = (wvh << 4) + cc;
        int n = (c << 6) + lane;
        float xx = pb[n * 3 + 0], yy = pb[n * 3 + 1], zz = pb[n * 3 + 2];
        float pnn = (xx * xx + yy * yy) + zz * zz;  // == old pn[n] bitwise
        float dot = __builtin_fmaf(sz, zz, __builtin_fmaf(sy, yy, sx * xx));
        float d2 = (sn + pnn) - 2.0f * dot;
        bool pred = d2 <= 0.04f;
        unsigned long long mask = __ballot(pred);
        if (lane == 0) masksL[c] = mask;
      }
    }
    __syncthreads();
    if (active && th < 64) {
      int pc = (int)__popcll(masksL[lane]);
      int incl = pc;
#pragma unroll
      for (int off = 1; off < 64; off <<= 1) {
        int o2 = __shfl_up(incl, off, 64);
        if (lane >= off) incl += o2;
      }
      prefixL[lane] = incl - pc;
      if (lane == 63) *cntS = incl < KK ? incl : KK;
    }
    __syncthreads();
    const int cnt = *cntS;
    if (active) {
#pragma unroll
      for (int cc = 0; cc < 16; ++cc) {
        int c = (wvh << 4) + cc;
        unsigned long long mk = masksL[c];
        bool pred = (mk >> lane) & 1ull;
        int slot = prefixL[c] + (int)__popcll(mk & ((1ull << lane) - 1ull));
        if (pred && slot < KK) nbr_s[slot] = (c << 6) + lane;
      }
    }
    __syncthreads();

    // ---- gather + hi/lo split into LDS feat planes ----
    if (active) {
      const int kn = th >> 2, p = th & 3;
      float vals[16];
      float d0 = 0.0f, d1 = 0.0f, d2v = 0.0f;
      if (kn < cnt) {
        int n = nbr_s[kn];
        const float* xp = x + ((size_t)b * NN + n) * CC + p * 16;
#pragma unroll
        for (int ii = 0; ii < 4; ++ii) {
          float4 v = ((const float4*)xp)[ii];
          vals[ii * 4 + 0] = v.x; vals[ii * 4 + 1] = v.y;
          vals[ii * 4 + 2] = v.z; vals[ii * 4 + 3] = v.w;
        }
        if (p == 0) {
          const float* pp = pos + ((size_t)b * NN + n) * 3;
          d0 = pp[0] - sx; d1 = pp[1] - sy; d2v = pp[2] - sz;
        }
      } else {
#pragma unroll
        for (int ii = 0; ii < 16; ++ii) vals[ii] = 0.0f;
      }
#pragma unroll
      for (int j = 0; j < 16; j += 2) {
        unsigned int h0, l0, h1, l1;
        split2(vals[j], h0, l0);
        split2(vals[j + 1], h1, l1);
        int c = p * 16 + j;
        *(unsigned int*)&Ah[kn * SA + c] = h0 | (h1 << 16);
        *(unsigned int*)&Al[kn * SA + c] = l0 | (l1 << 16);
      }
      if (p == 0) {
        unsigned int h0, l0, h1, l1, h2, l2;
        split2(d0, h0, l0); split2(d1, h1, l1); split2(d2v, h2, l2);
        *(unsigned int*)&Ah[kn * SA + 64] = h0 | (h1 << 16);
        *(unsigned int*)&Al[kn * SA + 64] = l0 | (l1 << 16);
        *(unsigned int*)&Ah[kn * SA + 66] = h2;
        *(unsigned int*)&Al[kn * SA + 66] = l2;
      } else if (p == 1) {
#pragma unroll
        for (int c = 68; c < 80; c += 2) {
          *(unsigned int*)&Ah[kn * SA + c] = 0u;
          *(unsigned int*)&Al[kn * SA + c] = 0u;
        }
      } else if (p == 2) {
#pragma unroll
        for (int c = 80; c < 96; c += 2) {
          *(unsigned int*)&Ah[kn * SA + c] = 0u;
          *(unsigned int*)&Al[kn * SA + c] = 0u;
        }
      }
    }
    __syncthreads();

    f32x4 acc[4][2];
#pragma unroll
    for (int mt = 0; mt < 4; ++mt)
#pragma unroll
      for (int nt = 0; nt < 2; ++nt) acc[mt][nt] = (f32x4)0.0f;

    // ---- layer 1 ----
    if (active) {
#pragma unroll
      for (int kc = 0; kc < 3; ++kc) {
        bf16x8 bh[2], bl[2];
#pragma unroll
        for (int nt = 0; nt < 2; ++nt) {
          int o = (wbase + nt * 16 + r) * KC1 + kc * 32 + q * 8;
          bh[nt] = *(const bf16x8*)(W1Th + o);
          bl[nt] = *(const bf16x8*)(W1Tl + o);
        }
#pragma unroll
        for (int mt = 0; mt < 4; ++mt) {
          int o = (mt * 16 + r) * SA + kc * 32 + q * 8;
          bf16x8 ah = *(const bf16x8*)&Ah[o];
          bf16x8 al = *(const bf16x8*)&Al[o];
#pragma unroll
          for (int nt = 0; nt < 2; ++nt) {
            acc[mt][nt] = __builtin_amdgcn_mfma_f32_16x16x32_bf16(ah, bh[nt], acc[mt][nt], 0, 0, 0);
            acc[mt][nt] = __builtin_amdgcn_mfma_f32_16x16x32_bf16(al, bh[nt], acc[mt][nt], 0, 0, 0);
            acc[mt][nt] = __builtin_amdgcn_mfma_f32_16x16x32_bf16(ah, bl[nt], acc[mt][nt], 0, 0, 0);
          }
        }
      }
    }
    __syncthreads();   // alias guard: A-plane reads done before H overwrite

    if (active) {
      float b1v[2] = { b1[wbase + r], b1[wbase + 16 + r] };
#pragma unroll
      for (int mt = 0; mt < 4; ++mt)
#pragma unroll
        for (int nt = 0; nt < 2; ++nt)
#pragma unroll
          for (int ii = 0; ii < 4; ++ii) {
            int mm = mt * 16 + q * 4 + ii;
            int n = wbase + nt * 16 + r;
            float v = fmaxf(acc[mt][nt][ii] + b1v[nt], 0.0f);
            unsigned int hh2, ll2; split2(v, hh2, ll2);
            Hh[mm * SH + n] = (unsigned short)hh2;
            Hl[mm * SH + n] = (unsigned short)ll2;
          }
    }
    __syncthreads();

    // ---- layer 2 + masked max ----
#pragma unroll
    for (int mt = 0; mt < 4; ++mt)
#pragma unroll
      for (int nt = 0; nt < 2; ++nt) acc[mt][nt] = (f32x4)0.0f;
    if (active) {
#pragma unroll
      for (int kc = 0; kc < 4; ++kc) {
        bf16x8 bh[2], bl[2];
#pragma unroll
        for (int nt = 0; nt < 2; ++nt) {
          int o = (wbase + nt * 16 + r) * HH + kc * 32 + q * 8;
          bh[nt] = *(const bf16x8*)(W2Th + o);
          bl[nt] = *(const bf16x8*)(W2Tl + o);
        }
#pragma unroll
        for (int mt = 0; mt < 4; ++mt) {
          int o = (mt * 16 + r) * SH + kc * 32 + q * 8;
          bf16x8 ah = *(const bf16x8*)&Hh[o];
          bf16x8 al = *(const bf16x8*)&Hl[o];
#pragma unroll
          for (int nt = 0; nt < 2; ++nt) {
            acc[mt][nt] = __builtin_amdgcn_mfma_f32_16x16x32_bf16(ah, bh[nt], acc[mt][nt], 0, 0, 0);
            acc[mt][nt] = __builtin_amdgcn_mfma_f32_16x16x32_bf16(al, bh[nt], acc[mt][nt], 0, 0, 0);
            acc[mt][nt] = __builtin_amdgcn_mfma_f32_16x16x32_bf16(ah, bl[nt], acc[mt][nt], 0, 0, 0);
          }
        }
      }
      float b2v[2] = { b2[wbase + r], b2[wbase + 16 + r] };
#pragma unroll
      for (int nt = 0; nt < 2; ++nt) {
        float vmax = NEGV;
#pragma unroll
        for (int mt = 0; mt < 4; ++mt)
#pragma unroll
          for (int ii = 0; ii < 4; ++ii) {
            int mm = mt * 16 + q * 4 + ii;
            float v = fmaxf(acc[mt][nt][ii] + b2v[nt], 0.0f);
            if (mm < cnt) vmax = fmaxf(vmax, v);
          }
        vmax = fmaxf(vmax, __shfl_xor(vmax, 16, 64));
        vmax = fmaxf(vmax, __shfl_xor(vmax, 32, 64));
        if (q == 0)
          out[(size_t)cid * HH + wbase + nt * 16 + r] = (cnt > 0) ? vmax : 0.0f;
      }
    }
    __syncthreads();   // LDS reuse guard before next center
  }
}

// ---------------------------------------------------------------------------
extern "C" void kernel_launch(void* const* d_in, const int* in_sizes, int n_in,
                              void* d_out, int out_size, void* d_ws, size_t ws_size,
                              hipStream_t stream) {
  const float* x   = (const float*)d_in[0];
  const float* pos = (const float*)d_in[1];
  const float* W1  = (const float*)d_in[2];
  const float* b1  = (const float*)d_in[3];
  const float* W2  = (const float*)d_in[4];
  const float* b2  = (const float*)d_in[5];
  float* out = (float*)d_out;
  float* pos_s_out = out + (size_t)BB * MM * HH;

  char* ws = (char*)d_ws;
  float* pos_s_ws = (float*)(ws);                          // 196608 B
  unsigned short* W1Th = (unsigned short*)(ws + 458752);   // 24576 B
  unsigned short* W1Tl = (unsigned short*)(ws + 483328);   // 24576 B
  unsigned short* W2Th = (unsigned short*)(ws + 507904);   // 32768 B
  unsigned short* W2Tl = (unsigned short*)(ws + 540672);   // 32768 B
  unsigned int* progress = (unsigned int*)(ws + 573440);   // 16*128 B
  unsigned int* claim    = (unsigned int*)(ws + 575488);   // 4 B

  wprep_kernel<<<HH, 128, 0, stream>>>(W1, W2, W1Th, W1Tl, W2Th, W2Tl,
                                       progress, claim);
  fused_kernel<<<GTOT, 512, 0, stream>>>(pos, x, pos_s_ws, pos_s_out,
                                         W1Th, W1Tl, W2Th, W2Tl, b1, b2, out,
                                         progress, claim);
}

// Round 7
// 749.435 us; speedup vs baseline: 2.0587x; 1.3489x over previous
//
#include <hip/hip_runtime.h>
#include <cstdint>
#include <cstddef>

#define BB 16
#define NN 4096
#define CC 64
#define MM 1024
#define KK 64
#define HH 128
#define NEGV -1.0e30f

#define FTH 256    // fps active threads (4 waves, 1/SIMD) — W-scan: 8 bad, 2 spills, 3-4 optimal
#define FPT 16     // points per thread (FTH*FPT == NN)
#define NPROD 16   // producer blocks (one per batch)
#define GTOT 256   // 1 block per CU
#define PSTRIDE 32 // progress counter stride in u32 (128B line per batch)

#define KC1 96     // layer-1 K dim padded (67 -> 96)
#define SA 104     // LDS stride of feat planes
#define SH 136     // LDS stride of h1 planes
#define HSTRIDE 41984  // per-half consumer LDS region

typedef __attribute__((ext_vector_type(8))) short bf16x8;
typedef __attribute__((ext_vector_type(4))) float f32x4;
typedef __attribute__((ext_vector_type(2))) float f32x2;

__device__ __forceinline__ unsigned int f2bf(float f) {
  unsigned int u = __float_as_uint(f);
  return (u + 0x7fffu + ((u >> 16) & 1u)) >> 16;
}
__device__ __forceinline__ void split2(float f, unsigned int& h, unsigned int& l) {
  h = f2bf(f);
  float hf = __uint_as_float(h << 16);
  l = f2bf(f - hf);
}

// f32 max across the wave via the proven DPP control sequence (R14-R18's
// u64 chain used identical ctrl/row-mask steps); lane 63 ends with the max.
template <int CTRL, int RM>
__device__ __forceinline__ float dppmaxf(float v) {
  int s = __builtin_amdgcn_update_dpp(__float_as_int(v), __float_as_int(v),
                                      CTRL, RM, 0xf, false);
  return fmaxf(v, __int_as_float(s));
}

// ---------------------------------------------------------------------------
// Weight prep + progress/claim init (block 0). pn computed inline by consumers.
// ---------------------------------------------------------------------------
__global__ __launch_bounds__(128) void wprep_kernel(
    const float* __restrict__ W1, const float* __restrict__ W2,
    unsigned short* __restrict__ W1Th, unsigned short* __restrict__ W1Tl,
    unsigned short* __restrict__ W2Th, unsigned short* __restrict__ W2Tl,
    unsigned int* __restrict__ progress, unsigned int* __restrict__ claim) {
  const int n = blockIdx.x, t = threadIdx.x;
  if (n == 0) {
    for (int j = t; j < NPROD * PSTRIDE; j += 128) progress[j] = 0u;
    if (t == 0) *claim = 0u;
  }
  if (t < KC1) {
    float v = (t < 67) ? W1[(size_t)t * HH + n] : 0.0f;
    unsigned int h, l; split2(v, h, l);
    W1Th[n * KC1 + t] = (unsigned short)h;
    W1Tl[n * KC1 + t] = (unsigned short)l;
  }
  {
    float v = W2[(size_t)t * HH + n];
    unsigned int h, l; split2(v, h, l);
    W2Th[n * HH + t] = (unsigned short)h;
    W2Tl[n * HH + t] = (unsigned short)l;
  }
}

// ---------------------------------------------------------------------------
// FUSED producer-consumer kernel, R21. Runtime == FPS critical path.
// R20 post-mortem: 2-wave producer spilled again (VGPR clamped at 128 by the
// allocator heuristic) -> 975us. Wave-scan fit: T(W) = 832/W + 92*W + c with
// c ~= 1150cy wave-invariant -> W=4 is optimal; attack c instead.
// R21 (vs R18, same 4-wave/FPT16 resources):
//  (1) RAW s_barrier in the loop (explicit lgkmcnt(0) + s_barrier + compiler
//      fence) instead of __syncthreads: kills the compiler's per-barrier
//      vmcnt(0) drain that stalled wave0 ~600cy after each flush (FPS waves
//      have no VMEM in the loop; flush stores retire off the barrier path).
//  (2) f32-max DPP reduce (6 fused v_max stages) + readlane(63) + ballot +
//      ctz + readlane(bi): replaces the u64 DPP chain, ~half the latency.
//      Requires CHUNK mapping i = t*16+j so first-set-lane == smallest
//      global index; with the left-biased tournament this preserves exact
//      first-max semantics -> selections bit-identical (absmax 0.015625).
//  (3) cand read as 2 x b128 (ulonglong2), one latency.
// Flush/release cadence identical to R18 (lanes 0-15 of wave0 flush at
// m%16==15; hand-rolled vmcnt(0)+relaxed release at m%16==0).
// ---------------------------------------------------------------------------
__global__ __launch_bounds__(512, 2) void fused_kernel(
    const float* __restrict__ pos, const float* __restrict__ x,
    float* __restrict__ pos_s_ws, float* __restrict__ pos_s_out,
    const unsigned short* __restrict__ W1Th, const unsigned short* __restrict__ W1Tl,
    const unsigned short* __restrict__ W2Th, const unsigned short* __restrict__ W2Tl,
    const float* __restrict__ b1, const float* __restrict__ b2,
    float* __restrict__ out,
    unsigned int* __restrict__ progress, unsigned int* __restrict__ claim) {
#pragma clang fp contract(off)
  __shared__ __attribute__((aligned(16))) unsigned char LBUF[83968];
  const int t = threadIdx.x;
  const int lane = t & 63;

  if (blockIdx.x < NPROD) {
    // =================== PRODUCER: FPS for batch b ===================
    if (t >= FTH) return;            // waves 4..7 exit; barrier counts live waves
    __builtin_amdgcn_s_setprio(3);
    const int wv = t >> 6;           // 0..3
    const int b = blockIdx.x;
    float4* P4 = (float4*)LBUF;                          // 65536 B
    float* SXa = (float*)(LBUF + 65536);                 // 4096 B
    float* SYa = (float*)(LBUF + 69632);                 // 4096 B
    float* SZa = (float*)(LBUF + 73728);                 // 4096 B
    unsigned long long* cand = (unsigned long long*)(LBUF + 77824); // [2][4]
    const float* pb = pos + (size_t)b * NN * 3;

    // (a) coalesced P4 fill (interleaved mapping, for broadcast reads)
#pragma unroll
    for (int j = 0; j < FPT; ++j) {
      int i = t + j * FTH;
      P4[i] = make_float4(pb[i * 3 + 0], pb[i * 3 + 1], pb[i * 3 + 2], 0.0f);
    }
    // (b) chunk-register fill: this thread owns points t*16 .. t*16+15
    //     (lane order == global index order -> ballot tie-break is exact)
    f32x2 px[8], py[8], pz[8], dd[8];
    {
      const float4* pc4 = (const float4*)(pb + (size_t)t * 48);
      float4 f4[12];
#pragma unroll
      for (int ii = 0; ii < 12; ++ii) f4[ii] = pc4[ii];
      const float* ff = (const float*)f4;
#pragma unroll
      for (int l = 0; l < 16; ++l) {
        px[l >> 1][l & 1] = ff[l * 3 + 0];
        py[l >> 1][l & 1] = ff[l * 3 + 1];
        pz[l >> 1][l & 1] = ff[l * 3 + 2];
        dd[l >> 1][l & 1] = 3.4028234663852886e38f;
      }
    }
    __syncthreads();
    float4 c4 = P4[0];
    float sx = c4.x, sy = c4.y, sz = c4.z;
    if (t == 0) { SXa[0] = sx; SYa[0] = sy; SZa[0] = sz; }

    for (int m = 1; m < MM; ++m) {
      f32x2 s2x = {sx, sx}, s2y = {sy, sy}, s2z = {sz, sz};
      // distance update + tournament L1 fused (left-biased: first-max kept)
      float tv[8]; int ti[8];
#pragma unroll
      for (int k = 0; k < 8; ++k) {
        f32x2 dx = px[k] - s2x, dy = py[k] - s2y, dz = pz[k] - s2z;
        f32x2 d2 = (dx * dx + dy * dy) + dz * dz;   // v_pk_*, no FMA (pragma)
        float n0 = fminf(dd[k][0], d2[0]);
        float n1 = fminf(dd[k][1], d2[1]);
        dd[k][0] = n0;
        dd[k][1] = n1;
        bool c = n1 > n0;
        tv[k] = c ? n1 : n0;
        ti[k] = c ? (2 * k + 1) : (2 * k);
      }
      // tournament L2..L4
      float uv[4]; int ui[4];
#pragma unroll
      for (int k = 0; k < 4; ++k) {
        bool c = tv[2 * k + 1] > tv[2 * k];
        uv[k] = c ? tv[2 * k + 1] : tv[2 * k];
        ui[k] = c ? ti[2 * k + 1] : ti[2 * k];
      }
      float wv2[2]; int wi2[2];
#pragma unroll
      for (int k = 0; k < 2; ++k) {
        bool c = uv[2 * k + 1] > uv[2 * k];
        wv2[k] = c ? uv[2 * k + 1] : uv[2 * k];
        wi2[k] = c ? ui[2 * k + 1] : ui[2 * k];
      }
      bool cf = wv2[1] > wv2[0];
      float bv = cf ? wv2[1] : wv2[0];
      int bj = cf ? wi2[1] : wi2[0];
      int bi = t * 16 + bj;            // global point index (chunk mapping)

      // fast wave reduce: value-only DPP max -> scalar tail
      float mx = bv;
      mx = dppmaxf<0x111, 0xf>(mx);
      mx = dppmaxf<0x112, 0xf>(mx);
      mx = dppmaxf<0x114, 0xf>(mx);
      mx = dppmaxf<0x118, 0xf>(mx);
      mx = dppmaxf<0x142, 0xa>(mx);
      mx = dppmaxf<0x143, 0xc>(mx);
      float wavemax = __int_as_float(
          __builtin_amdgcn_readlane(__float_as_int(mx), 63));
      unsigned long long ball = __ballot(bv == wavemax);
      int wl = (int)__builtin_ctzll(ball);       // lowest lane == smallest idx
      int wbi = __builtin_amdgcn_readlane(bi, wl);

      const int p4 = (m & 1) * 4;
      if (lane == 63) {
        unsigned long long key =
            ((unsigned long long)__float_as_uint(wavemax) << 32) |
            (unsigned long long)(~(unsigned int)wbi);
        cand[p4 + wv] = key;
      }
      // raw barrier: drain LDS (cand write) only — no vmcnt drain here.
      asm volatile("s_waitcnt lgkmcnt(0)" ::: "memory");
      __builtin_amdgcn_s_barrier();
      asm volatile("" ::: "memory");

      ulonglong2 cA = *(const ulonglong2*)(cand + p4);
      ulonglong2 cB = *(const ulonglong2*)(cand + p4 + 2);
      unsigned long long m01 = cA.x > cA.y ? cA.x : cA.y;
      unsigned long long m23 = cB.x > cB.y ? cB.x : cB.y;
      unsigned long long best = m01 > m23 ? m01 : m23;
      int fi = (int)(~(unsigned int)(best & 0xffffffffull));
      float4 w4 = P4[fi];
      sx = w4.x; sy = w4.y; sz = w4.z;
      if (t == 0) { SXa[m] = sx; SYa[m] = sy; SZa[m] = sz; }
      if ((m & 15) == 15) {
        // parallel flush: lanes 0..15 of wave0 each publish one center.
        // SXa[idx] written by lane0 of the SAME wave (in-order DS).
        if (t < 16) {
          int idx = (m - 15) + t;
          float fx = SXa[idx], fy = SYa[idx], fz = SZa[idx];
          size_t o = ((size_t)b * MM + idx) * 3;
          __hip_atomic_store(&pos_s_ws[o + 0], fx, __ATOMIC_RELAXED, __HIP_MEMORY_SCOPE_AGENT);
          __hip_atomic_store(&pos_s_ws[o + 1], fy, __ATOMIC_RELAXED, __HIP_MEMORY_SCOPE_AGENT);
          __hip_atomic_store(&pos_s_ws[o + 2], fz, __ATOMIC_RELAXED, __HIP_MEMORY_SCOPE_AGENT);
        }
      } else if ((m & 15) == 0 && t == 0) {
        // hand-rolled release: wave0's flush stores (issued one iter ago)
        // complete at the coherence point before progress publishes.
        asm volatile("s_waitcnt vmcnt(0)" ::: "memory");
        __hip_atomic_store(&progress[b * PSTRIDE], (unsigned int)m,
                           __ATOMIC_RELAXED, __HIP_MEMORY_SCOPE_AGENT);
      }
    }
    __syncthreads();   // full barrier: SXa final values visible to all threads
    if (t == 0) {
      // final publish: last flush (m=1023) covered centers 1008..1023.
      asm volatile("s_waitcnt vmcnt(0)" ::: "memory");
      __hip_atomic_store(&progress[b * PSTRIDE], (unsigned int)MM,
                         __ATOMIC_RELAXED, __HIP_MEMORY_SCOPE_AGENT);
    }
    for (int i = t; i < MM; i += FTH) {
      size_t o = ((size_t)b * MM + i) * 3;
      pos_s_out[o + 0] = SXa[i];
      pos_s_out[o + 1] = SYa[i];
      pos_s_out[o + 2] = SZa[i];
    }
    return;
  }

  // ============ CONSUMER: two 4-wave pipelines (halves h=0,1) ============
  const int h = t >> 8;            // half id
  const int th = t & 255;          // half-local thread id
  const int wvh = (t >> 6) & 3;    // half-local wave id
  unsigned char* HB = LBUF + h * HSTRIDE;
  unsigned short* Ah = (unsigned short*)HB;
  unsigned short* Al = (unsigned short*)(HB + 64 * SA * 2);
  unsigned short* Hh = (unsigned short*)HB;
  unsigned short* Hl = (unsigned short*)(HB + 64 * SH * 2);
  int* nbr_s = (int*)(HB + 34816);
  unsigned long long* masksL = (unsigned long long*)(HB + 35072);
  int* prefixL = (int*)(HB + 35584);
  float* ctr = (float*)(HB + 35840);
  int* cntS = (int*)(HB + 35856);
  volatile int* cidShare = (int*)(LBUF + 83960);   // block-wide
  const int r = lane & 15, q = lane >> 4;
  const int wbase = wvh * 32;

  while (true) {
    if (t == 0) {
      unsigned int i = __hip_atomic_fetch_add(claim, 2u, __ATOMIC_RELAXED,
                                              __HIP_MEMORY_SCOPE_AGENT);
      *cidShare = (int)i;
    }
    __syncthreads();
    int i0 = *cidShare;
    if (i0 >= BB * MM) break;                      // uniform exit
    const int i = i0 + h;
    const bool active = (i < BB * MM);
    const int cid = active ? (((i & 15) << 10) | (i >> 4)) : 0;
    const int b = cid >> 10;
    const int m = cid & 1023;

    if (active && th < 64) {   // half's wave 0 polls production progress
      while ((int)__hip_atomic_load(&progress[b * PSTRIDE], __ATOMIC_RELAXED,
                                    __HIP_MEMORY_SCOPE_AGENT) <= m)
        __builtin_amdgcn_s_sleep(64);
    }
    if (active && th < 3)
      ctr[th] = __hip_atomic_load(&pos_s_ws[(size_t)cid * 3 + th],
                                  __ATOMIC_RELAXED, __HIP_MEMORY_SCOPE_AGENT);
    __syncthreads();

    // ---- ballq: 4-wave mask pass + prefix + compaction (per half) ----
    const float sx = ctr[0], sy = ctr[1], sz = ctr[2];
    const float sn = (sx * sx + sy * sy) + sz * sz;
    const float* pb = pos + (size_t)b * NN * 3;
    if (active) {
#pragma unroll
      for (int cc = 0; cc < 16; ++cc) {
        int c = (wvh << 4) + cc;
        int n = (c << 6) + lane;
        float xx = pb[n * 3 + 0], yy = pb[n * 3 + 1], zz = pb[n * 3 + 2];
        float pnn = (xx * xx + yy * yy) + zz * zz;  // == old pn[n] bitwise
        float dot = __builtin_fmaf(sz, zz, __builtin_fmaf(sy, yy, sx * xx));
        float d2 = (sn + pnn) - 2.0f * dot;
        bool pred = d2 <= 0.04f;
        unsigned long long mask = __ballot(pred);
        if (lane == 0) masksL[c] = mask;
      }
    }
    __syncthreads();
    if (active && th < 64) {
      int pc = (int)__popcll(masksL[lane]);
      int incl = pc;
#pragma unroll
      for (int off = 1; off < 64; off <<= 1) {
        int o2 = __shfl_up(incl, off, 64);
        if (lane >= off) incl += o2;
      }
      prefixL[lane] = incl - pc;
      if (lane == 63) *cntS = incl < KK ? incl : KK;
    }
    __syncthreads();
    const int cnt = *cntS;
    if (active) {
#pragma unroll
      for (int cc = 0; cc < 16; ++cc) {
        int c = (wvh << 4) + cc;
        unsigned long long mk = masksL[c];
        bool pred = (mk >> lane) & 1ull;
        int slot = prefixL[c] + (int)__popcll(mk & ((1ull << lane) - 1ull));
        if (pred && slot < KK) nbr_s[slot] = (c << 6) + lane;
      }
    }
    __syncthreads();

    // ---- gather + hi/lo split into LDS feat planes ----
    if (active) {
      const int kn = th >> 2, p = th & 3;
      float vals[16];
      float d0 = 0.0f, d1 = 0.0f, d2v = 0.0f;
      if (kn < cnt) {
        int n = nbr_s[kn];
        const float* xp = x + ((size_t)b * NN + n) * CC + p * 16;
#pragma unroll
        for (int ii = 0; ii < 4; ++ii) {
          float4 v = ((const float4*)xp)[ii];
          vals[ii * 4 + 0] = v.x; vals[ii * 4 + 1] = v.y;
          vals[ii * 4 + 2] = v.z; vals[ii * 4 + 3] = v.w;
        }
        if (p == 0) {
          const float* pp = pos + ((size_t)b * NN + n) * 3;
          d0 = pp[0] - sx; d1 = pp[1] - sy; d2v = pp[2] - sz;
        }
      } else {
#pragma unroll
        for (int ii = 0; ii < 16; ++ii) vals[ii] = 0.0f;
      }
#pragma unroll
      for (int j = 0; j < 16; j += 2) {
        unsigned int h0, l0, h1, l1;
        split2(vals[j], h0, l0);
        split2(vals[j + 1], h1, l1);
        int c = p * 16 + j;
        *(unsigned int*)&Ah[kn * SA + c] = h0 | (h1 << 16);
        *(unsigned int*)&Al[kn * SA + c] = l0 | (l1 << 16);
      }
      if (p == 0) {
        unsigned int h0, l0, h1, l1, h2, l2;
        split2(d0, h0, l0); split2(d1, h1, l1); split2(d2v, h2, l2);
        *(unsigned int*)&Ah[kn * SA + 64] = h0 | (h1 << 16);
        *(unsigned int*)&Al[kn * SA + 64] = l0 | (l1 << 16);
        *(unsigned int*)&Ah[kn * SA + 66] = h2;
        *(unsigned int*)&Al[kn * SA + 66] = l2;
      } else if (p == 1) {
#pragma unroll
        for (int c = 68; c < 80; c += 2) {
          *(unsigned int*)&Ah[kn * SA + c] = 0u;
          *(unsigned int*)&Al[kn * SA + c] = 0u;
        }
      } else if (p == 2) {
#pragma unroll
        for (int c = 80; c < 96; c += 2) {
          *(unsigned int*)&Ah[kn * SA + c] = 0u;
          *(unsigned int*)&Al[kn * SA + c] = 0u;
        }
      }
    }
    __syncthreads();

    f32x4 acc[4][2];
#pragma unroll
    for (int mt = 0; mt < 4; ++mt)
#pragma unroll
      for (int nt = 0; nt < 2; ++nt) acc[mt][nt] = (f32x4)0.0f;

    // ---- layer 1 ----
    if (active) {
#pragma unroll
      for (int kc = 0; kc < 3; ++kc) {
        bf16x8 bh[2], bl[2];
#pragma unroll
        for (int nt = 0; nt < 2; ++nt) {
          int o = (wbase + nt * 16 + r) * KC1 + kc * 32 + q * 8;
          bh[nt] = *(const bf16x8*)(W1Th + o);
          bl[nt] = *(const bf16x8*)(W1Tl + o);
        }
#pragma unroll
        for (int mt = 0; mt < 4; ++mt) {
          int o = (mt * 16 + r) * SA + kc * 32 + q * 8;
          bf16x8 ah = *(const bf16x8*)&Ah[o];
          bf16x8 al = *(const bf16x8*)&Al[o];
#pragma unroll
          for (int nt = 0; nt < 2; ++nt) {
            acc[mt][nt] = __builtin_amdgcn_mfma_f32_16x16x32_bf16(ah, bh[nt], acc[mt][nt], 0, 0, 0);
            acc[mt][nt] = __builtin_amdgcn_mfma_f32_16x16x32_bf16(al, bh[nt], acc[mt][nt], 0, 0, 0);
            acc[mt][nt] = __builtin_amdgcn_mfma_f32_16x16x32_bf16(ah, bl[nt], acc[mt][nt], 0, 0, 0);
          }
        }
      }
    }
    __syncthreads();   // alias guard: A-plane reads done before H overwrite

    if (active) {
      float b1v[2] = { b1[wbase + r], b1[wbase + 16 + r] };
#pragma unroll
      for (int mt = 0; mt < 4; ++mt)
#pragma unroll
        for (int nt = 0; nt < 2; ++nt)
#pragma unroll
          for (int ii = 0; ii < 4; ++ii) {
            int mm = mt * 16 + q * 4 + ii;
            int n = wbase + nt * 16 + r;
            float v = fmaxf(acc[mt][nt][ii] + b1v[nt], 0.0f);
            unsigned int hh2, ll2; split2(v, hh2, ll2);
            Hh[mm * SH + n] = (unsigned short)hh2;
            Hl[mm * SH + n] = (unsigned short)ll2;
          }
    }
    __syncthreads();

    // ---- layer 2 + masked max ----
#pragma unroll
    for (int mt = 0; mt < 4; ++mt)
#pragma unroll
      for (int nt = 0; nt < 2; ++nt) acc[mt][nt] = (f32x4)0.0f;
    if (active) {
#pragma unroll
      for (int kc = 0; kc < 4; ++kc) {
        bf16x8 bh[2], bl[2];
#pragma unroll
        for (int nt = 0; nt < 2; ++nt) {
          int o = (wbase + nt * 16 + r) * HH + kc * 32 + q * 8;
          bh[nt] = *(const bf16x8*)(W2Th + o);
          bl[nt] = *(const bf16x8*)(W2Tl + o);
        }
#pragma unroll
        for (int mt = 0; mt < 4; ++mt) {
          int o = (mt * 16 + r) * SH + kc * 32 + q * 8;
          bf16x8 ah = *(const bf16x8*)&Hh[o];
          bf16x8 al = *(const bf16x8*)&Hl[o];
#pragma unroll
          for (int nt = 0; nt < 2; ++nt) {
            acc[mt][nt] = __builtin_amdgcn_mfma_f32_16x16x32_bf16(ah, bh[nt], acc[mt][nt], 0, 0, 0);
            acc[mt][nt] = __builtin_amdgcn_mfma_f32_16x16x32_bf16(al, bh[nt], acc[mt][nt], 0, 0, 0);
            acc[mt][nt] = __builtin_amdgcn_mfma_f32_16x16x32_bf16(ah, bl[nt], acc[mt][nt], 0, 0, 0);
          }
        }
      }
      float b2v[2] = { b2[wbase + r], b2[wbase + 16 + r] };
#pragma unroll
      for (int nt = 0; nt < 2; ++nt) {
        float vmax = NEGV;
#pragma unroll
        for (int mt = 0; mt < 4; ++mt)
#pragma unroll
          for (int ii = 0; ii < 4; ++ii) {
            int mm = mt * 16 + q * 4 + ii;
            float v = fmaxf(acc[mt][nt][ii] + b2v[nt], 0.0f);
            if (mm < cnt) vmax = fmaxf(vmax, v);
          }
        vmax = fmaxf(vmax, __shfl_xor(vmax, 16, 64));
        vmax = fmaxf(vmax, __shfl_xor(vmax, 32, 64));
        if (q == 0)
          out[(size_t)cid * HH + wbase + nt * 16 + r] = (cnt > 0) ? vmax : 0.0f;
      }
    }
    __syncthreads();   // LDS reuse guard before next center
  }
}

// ---------------------------------------------------------------------------
extern "C" void kernel_launch(void* const* d_in, const int* in_sizes, int n_in,
                              void* d_out, int out_size, void* d_ws, size_t ws_size,
                              hipStream_t stream) {
  const float* x   = (const float*)d_in[0];
  const float* pos = (const float*)d_in[1];
  const float* W1  = (const float*)d_in[2];
  const float* b1  = (const float*)d_in[3];
  const float* W2  = (const float*)d_in[4];
  const float* b2  = (const float*)d_in[5];
  float* out = (float*)d_out;
  float* pos_s_out = out + (size_t)BB * MM * HH;

  char* ws = (char*)d_ws;
  float* pos_s_ws = (float*)(ws);                          // 196608 B
  unsigned short* W1Th = (unsigned short*)(ws + 458752);   // 24576 B
  unsigned short* W1Tl = (unsigned short*)(ws + 483328);   // 24576 B
  unsigned short* W2Th = (unsigned short*)(ws + 507904);   // 32768 B
  unsigned short* W2Tl = (unsigned short*)(ws + 540672);   // 32768 B
  unsigned int* progress = (unsigned int*)(ws + 573440);   // 16*128 B
  unsigned int* claim    = (unsigned int*)(ws + 575488);   // 4 B

  wprep_kernel<<<HH, 128, 0, stream>>>(W1, W2, W1Th, W1Tl, W2Th, W2Tl,
                                       progress, claim);
  fused_kernel<<<GTOT, 512, 0, stream>>>(pos, x, pos_s_ws, pos_s_out,
                                         W1Th, W1Tl, W2Th, W2Tl, b1, b2, out,
                                         progress, claim);
}